// Round 8
// baseline (146.320 us; speedup 1.0000x reference)
//
#include <hip/hip_runtime.h>
#include <hip/hip_bf16.h>

// Problem constants (fixed by the reference model definition)
#define PAD        14
#define ACD        32
#define ATD        8
#define RCD        32
#define RID        32
#define N_CODES    38
#define N_TYPES    6
#define NCT        (N_CODES * N_TYPES)   // 228 combined code*6+type rows per slot
#define N_RES      21
#define MAX_SEQ    1024
#define IN0        624     // PAD*ACD + PAD*ATD + RCD + RID
#define OUT0       128
#define OUT1       32      // y1 channels (x3 coords = 96)
#define FEAT       224     // 128 + 96

// Unified projected-table row space (bf16 rows, 128 ch = 256B each)
#define NROWS_TCT  (PAD * NCT)           // 3192
#define ZROW       NROWS_TCT             // 3192: all-zero row (padded slots)
#define ROW_RC0    (ZROW + 1)            // 3193
#define ROW_RI0    (ROW_RC0 + N_RES)     // 3214
#define NROWS_ALL  (ROW_RI0 + MAX_SEQ)   // 4238

__device__ __constant__ const float NORM0 = 0.04003203845f;  // 1/sqrt(624)
__device__ __constant__ const float NORM1 = 0.26726124191f;  // 1/sqrt(14)

typedef float f32x2 __attribute__((ext_vector_type(2)));

#define SZ_W1N     (PAD * OUT1)          // 448 floats (W1 * NORM1)

// ---- Tier-2 (R4) f32 layout, used only if ws too small for fast path ------
#define T2_SZ_TCT     (PAD * NCT * OUT0)
#define T2_OFF_TCT    0
#define T2_OFF_TRC    (T2_OFF_TCT + T2_SZ_TCT)
#define T2_SZ_TRC     (N_RES * OUT0)
#define T2_OFF_TRI    (T2_OFF_TRC + T2_SZ_TRC)
#define T2_SZ_TRI     (MAX_SEQ * OUT0)
#define T2_OFF_W1N    (T2_OFF_TRI + T2_SZ_TRI)
#define T2_OFF_STARTS (T2_OFF_W1N + SZ_W1N)

__device__ __forceinline__ float bf_lo(unsigned int d) { return __uint_as_float(d << 16); }
__device__ __forceinline__ float bf_hi(unsigned int d) { return __uint_as_float(d & 0xffff0000u); }

// ---------------------------------------------------------------------------
// Kernel 1: per-residue start offsets (atoms sorted by residue, count>=1)
// + coalesced base_coords passthrough copy.
__global__ void build_starts(const int* __restrict__ resIdx, int n_atoms,
                             int* __restrict__ starts,
                             const float* __restrict__ baseIn,
                             float* __restrict__ outBase, int nbase) {
    int i = blockIdx.x * blockDim.x + threadIdx.x;
    if (i < nbase) outBase[i] = baseIn[i];
    if (i >= n_atoms) return;
    int r = resIdx[i];
    if (i == 0 || resIdx[i - 1] != r) starts[r] = i;
}

// ---------------------------------------------------------------------------
// Kernel 2 (fast path): build unified bf16 projected table (NORM0 folded) +
// zero row + W1n. Block b = row id; 128 threads = output channels.
__global__ void build_tall(const float* __restrict__ act, const float* __restrict__ att,
                           const float* __restrict__ rct, const float* __restrict__ rit,
                           const float* __restrict__ W0, const float* __restrict__ W1,
                           __hip_bfloat16* __restrict__ Tall, float* __restrict__ W1n) {
    int b = blockIdx.x;
    int o = threadIdx.x;  // 128 output channels (coalesced W0 column reads)
    float acc = 0.f;
    if (b < NROWS_TCT) {
        int m = b / NCT, ct = b % NCT, c = ct / N_TYPES, t = ct % N_TYPES;
        const float* wc = W0 + (size_t)(m * ACD) * OUT0 + o;
        const float* wt = W0 + (size_t)(PAD * ACD + m * ATD) * OUT0 + o;
#pragma unroll
        for (int j = 0; j < ACD; ++j) acc += act[c * ACD + j] * wc[(size_t)j * OUT0];
#pragma unroll
        for (int j = 0; j < ATD; ++j) acc += att[t * ATD + j] * wt[(size_t)j * OUT0];
        Tall[(size_t)b * OUT0 + o] = __float2bfloat16(acc * NORM0);
    } else if (b == ZROW) {
        Tall[(size_t)b * OUT0 + o] = __float2bfloat16(0.f);
    } else if (b < ROW_RC0 + N_RES) {
        int c = b - ROW_RC0;
        const float* w = W0 + (size_t)(PAD * ACD + PAD * ATD) * OUT0 + o;
#pragma unroll
        for (int j = 0; j < RCD; ++j) acc += rct[c * RCD + j] * w[(size_t)j * OUT0];
        Tall[(size_t)b * OUT0 + o] = __float2bfloat16(acc * NORM0);
    } else if (b < NROWS_ALL) {
        int s = b - ROW_RI0;
        const float* w = W0 + (size_t)(PAD * ACD + PAD * ATD + RCD) * OUT0 + o;
#pragma unroll
        for (int j = 0; j < RID; ++j) acc += rit[s * RID + j] * w[(size_t)j * OUT0];
        Tall[(size_t)b * OUT0 + o] = __float2bfloat16(acc * NORM0);
    } else {
        for (int i = o; i < PAD * OUT1; i += OUT0) W1n[i] = W1[i] * NORM1;
    }
}

// ---------------------------------------------------------------------------
// Kernel 3 (fast path): FULLY FUSED main. One wave per residue, straightline.
// All per-residue metadata read directly from the raw inputs as wave-uniform
// scalar loads (readfirstlane'd base pointers -> wide s_load; R7-proven
// pattern, no structs/refs). Row ids computed in SALU with uniform
// (m<cnt)?:ZROW selects; 16 unconditional bf16-row gathers; y1 = v_fma with
// SGPR coord operands (exact f32 coords). No meta buffer, no extra kernel.
__global__ __launch_bounds__(256) void main_fused(
    const float* __restrict__ coords,   // [n_atoms,3]
    const int*   __restrict__ codeIdx,  // [n_atoms]
    const int*   __restrict__ typeIdx,  // [n_atoms]
    const int*   __restrict__ counts,   // [R]
    const int*   __restrict__ rcIdx,    // [R]
    const int*   __restrict__ rsIdx,    // [R]
    const int*   __restrict__ starts,   // [R]
    const unsigned int* __restrict__ Tall,   // u32 view of bf16 rows
    const float* __restrict__ W1n,      // [14,32] pre-scaled by NORM1
    float* __restrict__ outFeat, int R, int n_atoms) {
    int lane   = threadIdx.x & 63;
    int lane32 = lane & 31;
    int wid    = threadIdx.x >> 6;
    int r = __builtin_amdgcn_readfirstlane(blockIdx.x * 4 + wid);
    if (r >= R) return;

    // y1 weights: 14 L1-hot dword vector loads (independent; issue early)
    float w14[PAD];
#pragma unroll
    for (int m = 0; m < PAD; ++m) w14[m] = W1n[m * OUT1 + lane32];

    int start = starts[r];              // all wave-uniform -> s_load
    int cnt   = counts[r];
    int rcrow = ROW_RC0 + rcIdx[r];
    int rirow = ROW_RI0 + rsIdx[r];

    // atom codes/types: 28 uniform dwords (wide s_load on the safe path;
    // only the last residue can be unsafe since start+cnt==n_atoms there)
    bool safe = (start + PAD) <= n_atoms;   // wave-uniform branch
    int c14[PAD], t14[PAD];
    if (safe) {
        const int* cp = codeIdx + start;
        const int* tp = typeIdx + start;
#pragma unroll
        for (int m = 0; m < PAD; ++m) { c14[m] = cp[m]; t14[m] = tp[m]; }
    } else {
#pragma unroll
        for (int m = 0; m < PAD; ++m) {
            int a = min(start + m, n_atoms - 1);
            c14[m] = codeIdx[a];
            t14[m] = typeIdx[a];
        }
    }

    // 16 table gathers, all independent and in flight together
    unsigned int t[16];
#pragma unroll
    for (int m = 0; m < PAD; ++m) {
        int row = (m < cnt) ? (m * NCT + c14[m] * N_TYPES + t14[m]) : ZROW;
        t[m] = Tall[(size_t)row * 64 + lane];
    }
    t[14] = Tall[(size_t)rcrow * 64 + lane];
    t[15] = Tall[(size_t)rirow * 64 + lane];

    // coords: 42 uniform dwords (s_load), consumed by y1 fmas while gathers fly
    float cf[3 * PAD];
    if (safe) {
        const float* cp = coords + (size_t)start * 3;
#pragma unroll
        for (int k = 0; k < 3 * PAD; ++k) cf[k] = cp[k];
    } else {
#pragma unroll
        for (int k = 0; k < 3 * PAD; ++k) {
            int i3 = min(start * 3 + k, n_atoms * 3 - 1);
            cf[k] = coords[i3];
        }
    }

    float vx = 0.f, vy = 0.f, vz = 0.f;
#pragma unroll
    for (int m = 0; m < PAD; ++m) {
        float cx = (m < cnt) ? cf[3 * m + 0] : 0.f;   // uniform select
        float cy = (m < cnt) ? cf[3 * m + 1] : 0.f;
        float cz = (m < cnt) ? cf[3 * m + 2] : 0.f;
        vx = fmaf(cx, w14[m], vx);
        vy = fmaf(cy, w14[m], vy);
        vz = fmaf(cz, w14[m], vz);
    }

    // y0: unpack bf16 pairs, accumulate the 16 rows
    float acx = 0.f, acy = 0.f;
#pragma unroll
    for (int j = 0; j < 16; ++j) {
        acx += bf_lo(t[j]);
        acy += bf_hi(t[j]);
    }

    float* fo = outFeat + (size_t)r * FEAT;
    f32x2 acc; acc.x = acx; acc.y = acy;
    __builtin_nontemporal_store(acc, reinterpret_cast<f32x2*>(fo) + lane);  // ch 0..127
    if (lane < 32) {
        float* p = fo + OUT0 + 3 * lane32;               // ch 128..223
        __builtin_nontemporal_store(vx, p + 0);
        __builtin_nontemporal_store(vy, p + 1);
        __builtin_nontemporal_store(vz, p + 2);
    }
}

// ---------------------------------------------------------------------------
// Tier-2 (R4 kernels, f32 tables) — used only when ws < fast-path need.
__global__ void build_tables_t2(const float* __restrict__ act, const float* __restrict__ att,
                                const float* __restrict__ rct, const float* __restrict__ rit,
                                const float* __restrict__ W0, const float* __restrict__ W1,
                                float* __restrict__ Tct, float* __restrict__ Trc,
                                float* __restrict__ Tri, float* __restrict__ W1n) {
    int b = blockIdx.x;
    int o = threadIdx.x;
    float acc = 0.f;
    if (b < PAD * NCT) {
        int m = b / NCT, ct = b % NCT, c = ct / N_TYPES, t = ct % N_TYPES;
        const float* wc = W0 + (size_t)(m * ACD) * OUT0 + o;
        const float* wt = W0 + (size_t)(PAD * ACD + m * ATD) * OUT0 + o;
#pragma unroll
        for (int j = 0; j < ACD; ++j) acc += act[c * ACD + j] * wc[(size_t)j * OUT0];
#pragma unroll
        for (int j = 0; j < ATD; ++j) acc += att[t * ATD + j] * wt[(size_t)j * OUT0];
        Tct[(size_t)b * OUT0 + o] = acc * NORM0;
    } else if (b < PAD * NCT + N_RES) {
        int c = b - PAD * NCT;
        const float* w = W0 + (size_t)(PAD * ACD + PAD * ATD) * OUT0 + o;
#pragma unroll
        for (int j = 0; j < RCD; ++j) acc += rct[c * RCD + j] * w[(size_t)j * OUT0];
        Trc[(size_t)c * OUT0 + o] = acc * NORM0;
    } else if (b < PAD * NCT + N_RES + MAX_SEQ) {
        int s = b - (PAD * NCT + N_RES);
        const float* w = W0 + (size_t)(PAD * ACD + PAD * ATD + RCD) * OUT0 + o;
#pragma unroll
        for (int j = 0; j < RID; ++j) acc += rit[s * RID + j] * w[(size_t)j * OUT0];
        Tri[(size_t)s * OUT0 + o] = acc * NORM0;
    } else {
        for (int i = o; i < PAD * OUT1; i += OUT0) W1n[i] = W1[i] * NORM1;
    }
}

__global__ __launch_bounds__(256) void main_t2(
    const float*  __restrict__ coords, const int* __restrict__ codeIdx,
    const int*    __restrict__ typeIdx, const int* __restrict__ counts,
    const int*    __restrict__ rcIdx, const int* __restrict__ rsIdx,
    const float*  __restrict__ W1n,
    const float*  __restrict__ Tct, const float* __restrict__ Trc,
    const float*  __restrict__ Tri, const int* __restrict__ starts,
    float* __restrict__ outFeat, int R, int n_atoms) {
    int wid  = threadIdx.x >> 6;
    int lane = threadIdx.x & 63;
    int r = __builtin_amdgcn_readfirstlane(blockIdx.x * 4 + wid);
    if (r >= R) return;
    int start = starts[r];
    int cnt   = counts[r];
    int rc    = rcIdx[r];
    int rs    = rsIdx[r];
    int lane32 = lane & 31;
    int ci = 1, ti = 1;
    float crd = 0.f;
    if (lane < PAD) {
        int a = min(start + lane, n_atoms - 1);
        ci = codeIdx[a];
        ti = typeIdx[a];
    }
    if (lane < 3 * PAD) {
        int i3 = min(start * 3 + lane, 3 * n_atoms - 1);
        crd = coords[i3];
    }
    const f32x2* Tct2 = reinterpret_cast<const f32x2*>(Tct);
    const f32x2* Trc2 = reinterpret_cast<const f32x2*>(Trc);
    const f32x2* Tri2 = reinterpret_cast<const f32x2*>(Tri);
    f32x2 a0 = Trc2[(size_t)rc * 64 + lane];
    f32x2 a1 = Tri2[(size_t)rs * 64 + lane];
    int cmax = max(cnt - 1, 0);
    f32x2 t[PAD];
#pragma unroll
    for (int m = 0; m < PAD; ++m) {
        int mm = min(m, cmax);
        int cd = __builtin_amdgcn_readlane(ci, mm);
        int tp = __builtin_amdgcn_readlane(ti, mm);
        t[m] = Tct2[(size_t)(mm * NCT + cd * N_TYPES + tp) * 64 + lane];
    }
    float acx = a0.x + a1.x;
    float acy = a0.y + a1.y;
    float vx = 0.f, vy = 0.f, vz = 0.f;
#pragma unroll
    for (int m = 0; m < PAD; ++m) {
        int mm = min(m, cmax);
        float msk = (m < cnt) ? 1.f : 0.f;
        acx = fmaf(t[m].x, msk, acx);
        acy = fmaf(t[m].y, msk, acy);
        float cx = __uint_as_float(__builtin_amdgcn_readlane(__float_as_uint(crd), 3 * mm + 0));
        float cy = __uint_as_float(__builtin_amdgcn_readlane(__float_as_uint(crd), 3 * mm + 1));
        float cz = __uint_as_float(__builtin_amdgcn_readlane(__float_as_uint(crd), 3 * mm + 2));
        float w  = W1n[m * OUT1 + lane32] * msk;
        vx = fmaf(cx, w, vx);
        vy = fmaf(cy, w, vy);
        vz = fmaf(cz, w, vz);
    }
    float* fo = outFeat + (size_t)r * FEAT;
    f32x2 accv; accv.x = acx; accv.y = acy;
    __builtin_nontemporal_store(accv, reinterpret_cast<f32x2*>(fo) + lane);
    if (lane < 32) {
        float* p = fo + OUT0 + 3 * lane32;
        __builtin_nontemporal_store(vx, p + 0);
        __builtin_nontemporal_store(vy, p + 1);
        __builtin_nontemporal_store(vz, p + 2);
    }
}

// ---------------------------------------------------------------------------
// Tier-3 fallback (tiny ws): direct per-residue dense dot.
__global__ __launch_bounds__(128) void fallback_kernel(
    const float* __restrict__ coords, const int* __restrict__ codeIdx,
    const int* __restrict__ typeIdx, const int* __restrict__ resIdx,
    const int* __restrict__ counts, const int* __restrict__ rcIdx,
    const int* __restrict__ rsIdx, const float* __restrict__ baseIn,
    const float* __restrict__ act, const float* __restrict__ att,
    const float* __restrict__ rct, const float* __restrict__ rit,
    const float* __restrict__ W0, const float* __restrict__ W1,
    float* __restrict__ outBase, float* __restrict__ outFeat, int R, int n_atoms) {
    int r = blockIdx.x, tid = threadIdx.x;
    __shared__ float s[IN0];
    __shared__ int sh_start;
    if (tid == 0) {
        int lo = 0, hi = n_atoms;
        while (lo < hi) { int mid = (lo + hi) >> 1; if (resIdx[mid] < r) lo = mid + 1; else hi = mid; }
        sh_start = lo;
    }
    __syncthreads();
    int start = sh_start, cnt = counts[r];
    for (int j = tid; j < IN0; j += 128) {
        float v = 0.f;
        if (j < PAD * ACD) {
            int m = j >> 5, jj = j & 31;
            if (m < cnt) v = act[codeIdx[start + m] * ACD + jj];
        } else if (j < PAD * ACD + PAD * ATD) {
            int t = j - PAD * ACD; int m = t >> 3, jj = t & 7;
            if (m < cnt) v = att[typeIdx[start + m] * ATD + jj];
        } else if (j < PAD * ACD + PAD * ATD + RCD) {
            v = rct[rcIdx[r] * RCD + (j - PAD * ACD - PAD * ATD)];
        } else {
            v = rit[rsIdx[r] * RID + (j - PAD * ACD - PAD * ATD - RCD)];
        }
        s[j] = v;
    }
    __syncthreads();
    float accv = 0.f;
    for (int j = 0; j < IN0; ++j) accv += s[j] * W0[(size_t)j * OUT0 + tid];
    float* fo = outFeat + (size_t)r * FEAT;
    fo[tid] = accv * NORM0;
    if (tid < 96) {
        int n = tid / 3, c = tid % 3;
        float v = 0.f;
        for (int m = 0; m < cnt; ++m) v += coords[(size_t)(start + m) * 3 + c] * W1[m * OUT1 + n];
        fo[OUT0 + tid] = v * NORM1;
    }
    if (tid < 3) outBase[(size_t)r * 3 + tid] = baseIn[(size_t)r * 3 + tid];
}

// ---------------------------------------------------------------------------
extern "C" void kernel_launch(void* const* d_in, const int* in_sizes, int n_in,
                              void* d_out, int out_size, void* d_ws, size_t ws_size,
                              hipStream_t stream) {
    const float* coords = (const float*)d_in[0];
    const int*   codeIdx = (const int*)d_in[1];
    const int*   typeIdx = (const int*)d_in[2];
    const int*   resIdx  = (const int*)d_in[3];
    const int*   counts  = (const int*)d_in[4];
    const int*   rcIdx   = (const int*)d_in[5];
    const int*   rsIdx   = (const int*)d_in[6];
    const float* baseIn  = (const float*)d_in[7];
    const float* act     = (const float*)d_in[8];
    const float* att     = (const float*)d_in[9];
    const float* rct     = (const float*)d_in[10];
    const float* rit     = (const float*)d_in[11];
    const float* W0      = (const float*)d_in[12];
    const float* W1      = (const float*)d_in[13];

    int n_atoms = in_sizes[1];
    int R       = in_sizes[4];

    float* out     = (float*)d_out;
    float* outBase = out;
    float* outFeat = out + (size_t)R * 3;

    // fast-path ws layout (bytes): bf16 table + W1n + starts  (~2.1 MB)
    size_t tallBytes = (size_t)NROWS_ALL * OUT0 * 2;
    size_t w1nOff    = tallBytes;
    size_t startsOff = w1nOff + (size_t)SZ_W1N * 4;
    size_t needFast  = startsOff + (size_t)R * 4;
    size_t needT2    = (size_t)(T2_OFF_STARTS + R) * 4;

    if (ws_size >= needFast) {
        char* wsb = (char*)d_ws;
        __hip_bfloat16* Tall   = (__hip_bfloat16*)wsb;
        unsigned int*   TallU  = (unsigned int*)wsb;
        float*          W1n    = (float*)(wsb + w1nOff);
        int*            starts = (int*)(wsb + startsOff);

        build_starts<<<(n_atoms + 255) / 256, 256, 0, stream>>>(
            resIdx, n_atoms, starts, baseIn, outBase, R * 3);
        build_tall<<<NROWS_ALL + 1, OUT0, 0, stream>>>(
            act, att, rct, rit, W0, W1, Tall, W1n);
        main_fused<<<(R + 3) / 4, 256, 0, stream>>>(
            coords, codeIdx, typeIdx, counts, rcIdx, rsIdx, starts,
            TallU, W1n, outFeat, R, n_atoms);
    } else if (ws_size >= needT2) {
        float* ws     = (float*)d_ws;
        float* Tct    = ws + T2_OFF_TCT;
        float* Trc    = ws + T2_OFF_TRC;
        float* Tri    = ws + T2_OFF_TRI;
        float* W1n    = ws + T2_OFF_W1N;
        int*   starts = (int*)(ws + T2_OFF_STARTS);
        build_starts<<<(n_atoms + 255) / 256, 256, 0, stream>>>(
            resIdx, n_atoms, starts, baseIn, outBase, R * 3);
        int nrows = PAD * NCT + N_RES + MAX_SEQ + 1;
        build_tables_t2<<<nrows, OUT0, 0, stream>>>(act, att, rct, rit, W0, W1,
                                                    Tct, Trc, Tri, W1n);
        main_t2<<<(R + 3) / 4, 256, 0, stream>>>(
            coords, codeIdx, typeIdx, counts, rcIdx, rsIdx, W1n,
            Tct, Trc, Tri, starts, outFeat, R, n_atoms);
    } else {
        fallback_kernel<<<R, 128, 0, stream>>>(
            coords, codeIdx, typeIdx, resIdx, counts, rcIdx, rsIdx, baseIn,
            act, att, rct, rit, W0, W1, outBase, outFeat, R, n_atoms);
    }
}

// Round 9
// 80.657 us; speedup vs baseline: 1.8141x; 1.8141x over previous
//
#include <hip/hip_runtime.h>
#include <hip/hip_bf16.h>

// Problem constants (fixed by the reference model definition)
#define PAD        14
#define ACD        32
#define ATD        8
#define RCD        32
#define RID        32
#define N_CODES    38
#define N_TYPES    6
#define NCT        (N_CODES * N_TYPES)   // 228 combined code*6+type rows per slot
#define N_RES      21
#define MAX_SEQ    1024
#define IN0        624     // PAD*ACD + PAD*ATD + RCD + RID
#define OUT0       128
#define OUT1       32      // y1 channels (x3 coords = 96)
#define FEAT       224     // 128 + 96

// Unified projected-table row space (bf16 rows, 128 ch = 256B each)
#define NROWS_TCT  (PAD * NCT)           // 3192
#define ZROW       NROWS_TCT             // 3192: all-zero row (padded slots)
#define ROW_RC0    (ZROW + 1)            // 3193
#define ROW_RI0    (ROW_RC0 + N_RES)     // 3214
#define NROWS_ALL  (ROW_RI0 + MAX_SEQ)   // 4238  (< 65536 -> u16 row ids)

__device__ __constant__ const float NORM0 = 0.04003203845f;  // 1/sqrt(624)
__device__ __constant__ const float NORM1 = 0.26726124191f;  // 1/sqrt(14)

typedef float f32x2 __attribute__((ext_vector_type(2)));

#define SZ_W1N     (PAD * OUT1)          // 448 floats (W1 * NORM1)

// ---- Tier-2 (R4) f32 layout, used only if ws too small for fast path ------
#define T2_SZ_TCT     (PAD * NCT * OUT0)
#define T2_OFF_TCT    0
#define T2_OFF_TRC    (T2_OFF_TCT + T2_SZ_TCT)
#define T2_SZ_TRC     (N_RES * OUT0)
#define T2_OFF_TRI    (T2_OFF_TRC + T2_SZ_TRC)
#define T2_SZ_TRI     (MAX_SEQ * OUT0)
#define T2_OFF_W1N    (T2_OFF_TRI + T2_SZ_TRI)
#define T2_OFF_STARTS (T2_OFF_W1N + SZ_W1N)

__device__ __forceinline__ unsigned short f2bf(float v) {
    __hip_bfloat16 h = __float2bfloat16(v);
    unsigned short u;
    __builtin_memcpy(&u, &h, 2);
    return u;
}
__device__ __forceinline__ float bf_lo(unsigned int d) { return __uint_as_float(d << 16); }
__device__ __forceinline__ float bf_hi(unsigned int d) { return __uint_as_float(d & 0xffff0000u); }

// ---------------------------------------------------------------------------
// Kernel 1: per-residue start offsets (atoms sorted by residue, count>=1)
// + coalesced base_coords passthrough copy.
__global__ void build_starts(const int* __restrict__ resIdx, int n_atoms,
                             int* __restrict__ starts,
                             const float* __restrict__ baseIn,
                             float* __restrict__ outBase, int nbase) {
    int i = blockIdx.x * blockDim.x + threadIdx.x;
    if (i < nbase) outBase[i] = baseIn[i];
    if (i >= n_atoms) return;
    int r = resIdx[i];
    if (i == 0 || resIdx[i - 1] != r) starts[r] = i;
}

// ---------------------------------------------------------------------------
// Kernel 2 (fast path): UNION grid — blocks [0, NROWS_ALL] build the unified
// bf16 projected table (NORM0 folded) + zero row + W1n (threads 0..127);
// blocks beyond that build the compact per-residue meta records (R7-proven
// layout, 128B = 64 u16):
//   u16[ 0..15] : table row ids (padded slots -> ZROW, 14 = Trc, 15 = Tri)
//   u16[16..29] : cx bf16[14], u16[32..45] : cy, u16[48..61] : cz
__global__ void build_tall_meta(
    const float* __restrict__ act, const float* __restrict__ att,
    const float* __restrict__ rct, const float* __restrict__ rit,
    const float* __restrict__ W0, const float* __restrict__ W1,
    __hip_bfloat16* __restrict__ Tall, float* __restrict__ W1n,
    const int* __restrict__ starts, const int* __restrict__ counts,
    const int* __restrict__ codeIdx, const int* __restrict__ typeIdx,
    const float* __restrict__ coords,
    const int* __restrict__ rcIdx, const int* __restrict__ rsIdx,
    unsigned short* __restrict__ meta, int R) {
    int b = blockIdx.x;
    if (b <= NROWS_ALL) {
        int o = threadIdx.x;  // 128 output channels (coalesced W0 column reads)
        if (o >= OUT0) return;
        float acc = 0.f;
        if (b < NROWS_TCT) {
            int m = b / NCT, ct = b % NCT, c = ct / N_TYPES, t = ct % N_TYPES;
            const float* wc = W0 + (size_t)(m * ACD) * OUT0 + o;
            const float* wt = W0 + (size_t)(PAD * ACD + m * ATD) * OUT0 + o;
#pragma unroll
            for (int j = 0; j < ACD; ++j) acc += act[c * ACD + j] * wc[(size_t)j * OUT0];
#pragma unroll
            for (int j = 0; j < ATD; ++j) acc += att[t * ATD + j] * wt[(size_t)j * OUT0];
            Tall[(size_t)b * OUT0 + o] = __float2bfloat16(acc * NORM0);
        } else if (b == ZROW) {
            Tall[(size_t)b * OUT0 + o] = __float2bfloat16(0.f);
        } else if (b < ROW_RC0 + N_RES) {
            int c = b - ROW_RC0;
            const float* w = W0 + (size_t)(PAD * ACD + PAD * ATD) * OUT0 + o;
#pragma unroll
            for (int j = 0; j < RCD; ++j) acc += rct[c * RCD + j] * w[(size_t)j * OUT0];
            Tall[(size_t)b * OUT0 + o] = __float2bfloat16(acc * NORM0);
        } else if (b < NROWS_ALL) {
            int s = b - ROW_RI0;
            const float* w = W0 + (size_t)(PAD * ACD + PAD * ATD + RCD) * OUT0 + o;
#pragma unroll
            for (int j = 0; j < RID; ++j) acc += rit[s * RID + j] * w[(size_t)j * OUT0];
            Tall[(size_t)b * OUT0 + o] = __float2bfloat16(acc * NORM0);
        } else {
            for (int i = o; i < PAD * OUT1; i += OUT0) W1n[i] = W1[i] * NORM1;
        }
        return;
    }
    // meta path: 16 threads per residue
    int gid = (b - (NROWS_ALL + 1)) * 256 + threadIdx.x;
    int r = gid >> 4, slot = gid & 15;
    if (r >= R) return;
    unsigned short* mp = meta + (size_t)r * 64;
    if (slot < PAD) {
        int cnt = counts[r];
        int row = ZROW;
        float cx = 0.f, cy = 0.f, cz = 0.f;
        if (slot < cnt) {
            int a = starts[r] + slot;
            row = slot * NCT + codeIdx[a] * N_TYPES + typeIdx[a];
            cx = coords[3 * (size_t)a + 0];
            cy = coords[3 * (size_t)a + 1];
            cz = coords[3 * (size_t)a + 2];
        }
        mp[slot]      = (unsigned short)row;
        mp[16 + slot] = f2bf(cx);
        mp[32 + slot] = f2bf(cy);
        mp[48 + slot] = f2bf(cz);
    } else if (slot == 14) {
        mp[14] = (unsigned short)(ROW_RC0 + rcIdx[r]);
    } else {
        mp[15] = (unsigned short)(ROW_RI0 + rsIdx[r]);
    }
}

// ---------------------------------------------------------------------------
// Kernel 3 (fast path): TWO RESIDUES PER WAVE, straightline, no loop.
// One contiguous 256B meta read (wide s_load, single latency), 32 table
// gathers all in flight, w14 loaded once per wave. Plain-int scalarized
// loads from readfirstlane'd uniform pointer (R7-proven; NO structs/refs —
// R6's scratch-spill trap). Zero-row absorbs padding. 100k independent waves.
__global__ __launch_bounds__(256) void main_fast2(
    const int* __restrict__ meta32,          // int view of meta records
    const unsigned int* __restrict__ Tall,   // u32 view of bf16 rows
    const float* __restrict__ W1n,
    float* __restrict__ outFeat, int R) {
    int lane   = threadIdx.x & 63;
    int lane32 = lane & 31;
    int wid    = threadIdx.x >> 6;
    int pr = __builtin_amdgcn_readfirstlane(blockIdx.x * 4 + wid);  // pair idx
    int r0 = pr * 2;
    if (r0 >= R) return;
    bool has1 = (r0 + 1) < R;   // wave-uniform

    // y1 weights: 14 L1-hot dword loads, once per wave
    float w14[PAD];
#pragma unroll
    for (int m = 0; m < PAD; ++m) w14[m] = W1n[m * OUT1 + lane32];

    const int* mp = meta32 + (size_t)r0 * 32;
    int md[64];
#pragma unroll
    for (int j = 0; j < 32; ++j) md[j] = mp[j];      // uniform -> wide s_load
    if (has1) {
#pragma unroll
        for (int j = 32; j < 64; ++j) md[j] = mp[j];
    } else {
#pragma unroll
        for (int j = 32; j < 64; ++j) md[j] = 0;
    }

    // 32 table gathers, all independent and in flight together
    unsigned int t0[16], t1[16];
#pragma unroll
    for (int k = 0; k < 8; ++k) {
        unsigned int dw = (unsigned int)md[k];
        t0[2 * k]     = Tall[(size_t)(dw & 0xffffu) * 64 + lane];
        t0[2 * k + 1] = Tall[(size_t)(dw >> 16) * 64 + lane];
    }
    if (has1) {
#pragma unroll
        for (int k = 0; k < 8; ++k) {
            unsigned int dw = (unsigned int)md[32 + k];
            t1[2 * k]     = Tall[(size_t)(dw & 0xffffu) * 64 + lane];
            t1[2 * k + 1] = Tall[(size_t)(dw >> 16) * 64 + lane];
        }
    }

    // y1 for both residues: coords unpacked from SGPR bf16 pairs (SALU),
    // fmac with SGPR src — overlaps with the gathers in flight
    float vx0 = 0.f, vy0 = 0.f, vz0 = 0.f;
    float vx1 = 0.f, vy1 = 0.f, vz1 = 0.f;
#pragma unroll
    for (int m = 0; m < PAD; ++m) {
        int dw = m >> 1;
        unsigned int xd0 = (unsigned int)md[8 + dw];
        unsigned int yd0 = (unsigned int)md[16 + dw];
        unsigned int zd0 = (unsigned int)md[24 + dw];
        float cx0 = (m & 1) ? bf_hi(xd0) : bf_lo(xd0);
        float cy0 = (m & 1) ? bf_hi(yd0) : bf_lo(yd0);
        float cz0 = (m & 1) ? bf_hi(zd0) : bf_lo(zd0);
        vx0 = fmaf(cx0, w14[m], vx0);
        vy0 = fmaf(cy0, w14[m], vy0);
        vz0 = fmaf(cz0, w14[m], vz0);
        unsigned int xd1 = (unsigned int)md[40 + dw];
        unsigned int yd1 = (unsigned int)md[48 + dw];
        unsigned int zd1 = (unsigned int)md[56 + dw];
        float cx1 = (m & 1) ? bf_hi(xd1) : bf_lo(xd1);
        float cy1 = (m & 1) ? bf_hi(yd1) : bf_lo(yd1);
        float cz1 = (m & 1) ? bf_hi(zd1) : bf_lo(zd1);
        vx1 = fmaf(cx1, w14[m], vx1);
        vy1 = fmaf(cy1, w14[m], vy1);
        vz1 = fmaf(cz1, w14[m], vz1);
    }

    // y0 residue 0
    float acx0 = 0.f, acy0 = 0.f;
#pragma unroll
    for (int j = 0; j < 16; ++j) { acx0 += bf_lo(t0[j]); acy0 += bf_hi(t0[j]); }

    float* fo0 = outFeat + (size_t)r0 * FEAT;
    f32x2 a0; a0.x = acx0; a0.y = acy0;
    __builtin_nontemporal_store(a0, reinterpret_cast<f32x2*>(fo0) + lane);
    if (lane < 32) {
        float* p = fo0 + OUT0 + 3 * lane32;
        __builtin_nontemporal_store(vx0, p + 0);
        __builtin_nontemporal_store(vy0, p + 1);
        __builtin_nontemporal_store(vz0, p + 2);
    }

    if (has1) {
        float acx1 = 0.f, acy1 = 0.f;
#pragma unroll
        for (int j = 0; j < 16; ++j) { acx1 += bf_lo(t1[j]); acy1 += bf_hi(t1[j]); }
        float* fo1 = fo0 + FEAT;
        f32x2 a1; a1.x = acx1; a1.y = acy1;
        __builtin_nontemporal_store(a1, reinterpret_cast<f32x2*>(fo1) + lane);
        if (lane < 32) {
            float* p = fo1 + OUT0 + 3 * lane32;
            __builtin_nontemporal_store(vx1, p + 0);
            __builtin_nontemporal_store(vy1, p + 1);
            __builtin_nontemporal_store(vz1, p + 2);
        }
    }
}

// ---------------------------------------------------------------------------
// Tier-2 (R4 kernels, f32 tables) — used only when ws < fast-path need.
__global__ void build_tables_t2(const float* __restrict__ act, const float* __restrict__ att,
                                const float* __restrict__ rct, const float* __restrict__ rit,
                                const float* __restrict__ W0, const float* __restrict__ W1,
                                float* __restrict__ Tct, float* __restrict__ Trc,
                                float* __restrict__ Tri, float* __restrict__ W1n) {
    int b = blockIdx.x;
    int o = threadIdx.x;
    float acc = 0.f;
    if (b < PAD * NCT) {
        int m = b / NCT, ct = b % NCT, c = ct / N_TYPES, t = ct % N_TYPES;
        const float* wc = W0 + (size_t)(m * ACD) * OUT0 + o;
        const float* wt = W0 + (size_t)(PAD * ACD + m * ATD) * OUT0 + o;
#pragma unroll
        for (int j = 0; j < ACD; ++j) acc += act[c * ACD + j] * wc[(size_t)j * OUT0];
#pragma unroll
        for (int j = 0; j < ATD; ++j) acc += att[t * ATD + j] * wt[(size_t)j * OUT0];
        Tct[(size_t)b * OUT0 + o] = acc * NORM0;
    } else if (b < PAD * NCT + N_RES) {
        int c = b - PAD * NCT;
        const float* w = W0 + (size_t)(PAD * ACD + PAD * ATD) * OUT0 + o;
#pragma unroll
        for (int j = 0; j < RCD; ++j) acc += rct[c * RCD + j] * w[(size_t)j * OUT0];
        Trc[(size_t)c * OUT0 + o] = acc * NORM0;
    } else if (b < PAD * NCT + N_RES + MAX_SEQ) {
        int s = b - (PAD * NCT + N_RES);
        const float* w = W0 + (size_t)(PAD * ACD + PAD * ATD + RCD) * OUT0 + o;
#pragma unroll
        for (int j = 0; j < RID; ++j) acc += rit[s * RID + j] * w[(size_t)j * OUT0];
        Tri[(size_t)s * OUT0 + o] = acc * NORM0;
    } else {
        for (int i = o; i < PAD * OUT1; i += OUT0) W1n[i] = W1[i] * NORM1;
    }
}

__global__ __launch_bounds__(256) void main_t2(
    const float*  __restrict__ coords, const int* __restrict__ codeIdx,
    const int*    __restrict__ typeIdx, const int* __restrict__ counts,
    const int*    __restrict__ rcIdx, const int* __restrict__ rsIdx,
    const float*  __restrict__ W1n,
    const float*  __restrict__ Tct, const float* __restrict__ Trc,
    const float*  __restrict__ Tri, const int* __restrict__ starts,
    float* __restrict__ outFeat, int R, int n_atoms) {
    int wid  = threadIdx.x >> 6;
    int lane = threadIdx.x & 63;
    int r = __builtin_amdgcn_readfirstlane(blockIdx.x * 4 + wid);
    if (r >= R) return;
    int start = starts[r];
    int cnt   = counts[r];
    int rc    = rcIdx[r];
    int rs    = rsIdx[r];
    int lane32 = lane & 31;
    int ci = 1, ti = 1;
    float crd = 0.f;
    if (lane < PAD) {
        int a = min(start + lane, n_atoms - 1);
        ci = codeIdx[a];
        ti = typeIdx[a];
    }
    if (lane < 3 * PAD) {
        int i3 = min(start * 3 + lane, 3 * n_atoms - 1);
        crd = coords[i3];
    }
    const f32x2* Tct2 = reinterpret_cast<const f32x2*>(Tct);
    const f32x2* Trc2 = reinterpret_cast<const f32x2*>(Trc);
    const f32x2* Tri2 = reinterpret_cast<const f32x2*>(Tri);
    f32x2 a0 = Trc2[(size_t)rc * 64 + lane];
    f32x2 a1 = Tri2[(size_t)rs * 64 + lane];
    int cmax = max(cnt - 1, 0);
    f32x2 t[PAD];
#pragma unroll
    for (int m = 0; m < PAD; ++m) {
        int mm = min(m, cmax);
        int cd = __builtin_amdgcn_readlane(ci, mm);
        int tp = __builtin_amdgcn_readlane(ti, mm);
        t[m] = Tct2[(size_t)(mm * NCT + cd * N_TYPES + tp) * 64 + lane];
    }
    float acx = a0.x + a1.x;
    float acy = a0.y + a1.y;
    float vx = 0.f, vy = 0.f, vz = 0.f;
#pragma unroll
    for (int m = 0; m < PAD; ++m) {
        int mm = min(m, cmax);
        float msk = (m < cnt) ? 1.f : 0.f;
        acx = fmaf(t[m].x, msk, acx);
        acy = fmaf(t[m].y, msk, acy);
        float cx = __uint_as_float(__builtin_amdgcn_readlane(__float_as_uint(crd), 3 * mm + 0));
        float cy = __uint_as_float(__builtin_amdgcn_readlane(__float_as_uint(crd), 3 * mm + 1));
        float cz = __uint_as_float(__builtin_amdgcn_readlane(__float_as_uint(crd), 3 * mm + 2));
        float w  = W1n[m * OUT1 + lane32] * msk;
        vx = fmaf(cx, w, vx);
        vy = fmaf(cy, w, vy);
        vz = fmaf(cz, w, vz);
    }
    float* fo = outFeat + (size_t)r * FEAT;
    f32x2 accv; accv.x = acx; accv.y = acy;
    __builtin_nontemporal_store(accv, reinterpret_cast<f32x2*>(fo) + lane);
    if (lane < 32) {
        float* p = fo + OUT0 + 3 * lane32;
        __builtin_nontemporal_store(vx, p + 0);
        __builtin_nontemporal_store(vy, p + 1);
        __builtin_nontemporal_store(vz, p + 2);
    }
}

// ---------------------------------------------------------------------------
// Tier-3 fallback (tiny ws): direct per-residue dense dot.
__global__ __launch_bounds__(128) void fallback_kernel(
    const float* __restrict__ coords, const int* __restrict__ codeIdx,
    const int* __restrict__ typeIdx, const int* __restrict__ resIdx,
    const int* __restrict__ counts, const int* __restrict__ rcIdx,
    const int* __restrict__ rsIdx, const float* __restrict__ baseIn,
    const float* __restrict__ act, const float* __restrict__ att,
    const float* __restrict__ rct, const float* __restrict__ rit,
    const float* __restrict__ W0, const float* __restrict__ W1,
    float* __restrict__ outBase, float* __restrict__ outFeat, int R, int n_atoms) {
    int r = blockIdx.x, tid = threadIdx.x;
    __shared__ float s[IN0];
    __shared__ int sh_start;
    if (tid == 0) {
        int lo = 0, hi = n_atoms;
        while (lo < hi) { int mid = (lo + hi) >> 1; if (resIdx[mid] < r) lo = mid + 1; else hi = mid; }
        sh_start = lo;
    }
    __syncthreads();
    int start = sh_start, cnt = counts[r];
    for (int j = tid; j < IN0; j += 128) {
        float v = 0.f;
        if (j < PAD * ACD) {
            int m = j >> 5, jj = j & 31;
            if (m < cnt) v = act[codeIdx[start + m] * ACD + jj];
        } else if (j < PAD * ACD + PAD * ATD) {
            int t = j - PAD * ACD; int m = t >> 3, jj = t & 7;
            if (m < cnt) v = att[typeIdx[start + m] * ATD + jj];
        } else if (j < PAD * ACD + PAD * ATD + RCD) {
            v = rct[rcIdx[r] * RCD + (j - PAD * ACD - PAD * ATD)];
        } else {
            v = rit[rsIdx[r] * RID + (j - PAD * ACD - PAD * ATD - RCD)];
        }
        s[j] = v;
    }
    __syncthreads();
    float accv = 0.f;
    for (int j = 0; j < IN0; ++j) accv += s[j] * W0[(size_t)j * OUT0 + tid];
    float* fo = outFeat + (size_t)r * FEAT;
    fo[tid] = accv * NORM0;
    if (tid < 96) {
        int n = tid / 3, c = tid % 3;
        float v = 0.f;
        for (int m = 0; m < cnt; ++m) v += coords[(size_t)(start + m) * 3 + c] * W1[m * OUT1 + n];
        fo[OUT0 + tid] = v * NORM1;
    }
    if (tid < 3) outBase[(size_t)r * 3 + tid] = baseIn[(size_t)r * 3 + tid];
}

// ---------------------------------------------------------------------------
extern "C" void kernel_launch(void* const* d_in, const int* in_sizes, int n_in,
                              void* d_out, int out_size, void* d_ws, size_t ws_size,
                              hipStream_t stream) {
    const float* coords = (const float*)d_in[0];
    const int*   codeIdx = (const int*)d_in[1];
    const int*   typeIdx = (const int*)d_in[2];
    const int*   resIdx  = (const int*)d_in[3];
    const int*   counts  = (const int*)d_in[4];
    const int*   rcIdx   = (const int*)d_in[5];
    const int*   rsIdx   = (const int*)d_in[6];
    const float* baseIn  = (const float*)d_in[7];
    const float* act     = (const float*)d_in[8];
    const float* att     = (const float*)d_in[9];
    const float* rct     = (const float*)d_in[10];
    const float* rit     = (const float*)d_in[11];
    const float* W0      = (const float*)d_in[12];
    const float* W1      = (const float*)d_in[13];

    int n_atoms = in_sizes[1];
    int R       = in_sizes[4];

    float* out     = (float*)d_out;
    float* outBase = out;
    float* outFeat = out + (size_t)R * 3;

    // fast-path ws layout (bytes)
    size_t tallBytes = (size_t)NROWS_ALL * OUT0 * 2;            // bf16 rows (1.08 MB)
    size_t w1nOff    = tallBytes;
    size_t startsOff = w1nOff + (size_t)SZ_W1N * 4;
    size_t metaOff   = (startsOff + (size_t)R * 4 + 255) & ~(size_t)255;
    size_t needFast  = metaOff + (size_t)R * 128;
    size_t needT2    = (size_t)(T2_OFF_STARTS + R) * 4;

    if (ws_size >= needFast) {
        char* wsb = (char*)d_ws;
        __hip_bfloat16* Tall   = (__hip_bfloat16*)wsb;
        unsigned int*   TallU  = (unsigned int*)wsb;
        float*          W1n    = (float*)(wsb + w1nOff);
        int*            starts = (int*)(wsb + startsOff);
        unsigned short* meta   = (unsigned short*)(wsb + metaOff);
        int*            meta32 = (int*)(wsb + metaOff);

        build_starts<<<(n_atoms + 255) / 256, 256, 0, stream>>>(
            resIdx, n_atoms, starts, baseIn, outBase, R * 3);
        int metaBlocks = (int)(((size_t)R * 16 + 255) / 256);
        build_tall_meta<<<(NROWS_ALL + 1) + metaBlocks, 256, 0, stream>>>(
            act, att, rct, rit, W0, W1, Tall, W1n,
            starts, counts, codeIdx, typeIdx, coords, rcIdx, rsIdx, meta, R);
        int pairs = (R + 1) / 2;
        main_fast2<<<(pairs + 3) / 4, 256, 0, stream>>>(
            meta32, TallU, W1n, outFeat, R);
    } else if (ws_size >= needT2) {
        float* ws     = (float*)d_ws;
        float* Tct    = ws + T2_OFF_TCT;
        float* Trc    = ws + T2_OFF_TRC;
        float* Tri    = ws + T2_OFF_TRI;
        float* W1n    = ws + T2_OFF_W1N;
        int*   starts = (int*)(ws + T2_OFF_STARTS);
        build_starts<<<(n_atoms + 255) / 256, 256, 0, stream>>>(
            resIdx, n_atoms, starts, baseIn, outBase, R * 3);
        int nrows = PAD * NCT + N_RES + MAX_SEQ + 1;
        build_tables_t2<<<nrows, OUT0, 0, stream>>>(act, att, rct, rit, W0, W1,
                                                    Tct, Trc, Tri, W1n);
        main_t2<<<(R + 3) / 4, 256, 0, stream>>>(
            coords, codeIdx, typeIdx, counts, rcIdx, rsIdx, W1n,
            Tct, Trc, Tri, starts, outFeat, R, n_atoms);
    } else {
        fallback_kernel<<<R, 128, 0, stream>>>(
            coords, codeIdx, typeIdx, resIdx, counts, rcIdx, rsIdx, baseIn,
            act, att, rct, rit, W0, W1, outBase, outFeat, R, n_atoms);
    }
}